// Round 1
// baseline (2728.678 us; speedup 1.0000x reference)
//
#include <hip/hip_runtime.h>
#include <hip/hip_bf16.h>

// SimpleRNN: B=64, S=2048, IN=256, H=128, OUT=3 (all fp32)
// Phase 1: xproj[b,s,:] = x[b,s,:] @ W_xh^T + b_xh   -> d_ws (64 MB)
// Phase 2: 2048-step recurrence, 1 workgroup (1 wave) per batch element,
//          W_hh rows register-resident, h in LDS, fused final FC to d_out.

#define RNN_B   64
#define RNN_S   2048
#define RNN_IN  256
#define RNN_H   128
#define RNN_OUT 3

// ---------------------------------------------------------------------------
// Phase 1: fp32 tiled GEMM  C[M=131072, N=128] = A[M,256] * B[128,256]^T
// Tile: BM=128, BN=128, BK=32; 256 threads, 8x8 per-thread tile.
// ---------------------------------------------------------------------------
__global__ __launch_bounds__(256) void xproj_gemm(
    const float* __restrict__ x, const float* __restrict__ Wxh,
    const float* __restrict__ bxh, float* __restrict__ xp) {
  __shared__ float As[32][129];  // [k][m], +1 pad
  __shared__ float Bs[32][129];  // [k][n], +1 pad

  const int tid = threadIdx.x;
  const int m0 = blockIdx.x * 128;
  const int tn = (tid & 15) * 8;   // n offset 0..120
  const int tm = (tid >> 4) * 8;   // m offset 0..120

  float acc[8][8];
#pragma unroll
  for (int i = 0; i < 8; ++i)
#pragma unroll
    for (int j = 0; j < 8; ++j) acc[i][j] = 0.f;

  const int c = (tid & 7) * 4;   // k sub-col (float4)
  const int r0 = tid >> 3;       // row 0..31

  for (int kc = 0; kc < RNN_IN; kc += 32) {
#pragma unroll
    for (int p = 0; p < 4; ++p) {
      const int row = r0 + 32 * p;
      const float4 va = *(const float4*)&x[(size_t)(m0 + row) * RNN_IN + kc + c];
      As[c + 0][row] = va.x; As[c + 1][row] = va.y;
      As[c + 2][row] = va.z; As[c + 3][row] = va.w;
      const float4 vb = *(const float4*)&Wxh[(size_t)row * RNN_IN + kc + c];
      Bs[c + 0][row] = vb.x; Bs[c + 1][row] = vb.y;
      Bs[c + 2][row] = vb.z; Bs[c + 3][row] = vb.w;
    }
    __syncthreads();
#pragma unroll
    for (int k = 0; k < 32; ++k) {
      float a[8], b[8];
#pragma unroll
      for (int j = 0; j < 8; ++j) { a[j] = As[k][tm + j]; b[j] = Bs[k][tn + j]; }
#pragma unroll
      for (int i = 0; i < 8; ++i)
#pragma unroll
        for (int j = 0; j < 8; ++j) acc[i][j] += a[i] * b[j];
    }
    __syncthreads();
  }

  // epilogue: add b_xh, store
#pragma unroll
  for (int i = 0; i < 8; ++i) {
    const size_t row = (size_t)(m0 + tm + i);
#pragma unroll
    for (int j = 0; j < 8; j += 4) {
      float4 v;
      v.x = acc[i][j + 0] + bxh[tn + j + 0];
      v.y = acc[i][j + 1] + bxh[tn + j + 1];
      v.z = acc[i][j + 2] + bxh[tn + j + 2];
      v.w = acc[i][j + 3] + bxh[tn + j + 3];
      *(float4*)&xp[row * RNN_H + tn + j] = v;
    }
  }
}

// fast tanh: 1 - 2/(exp(2x)+1); correct saturation at +-inf via __expf
__device__ __forceinline__ float fast_tanh(float a) {
  const float e = __expf(2.f * a);
  return 1.f - 2.f / (e + 1.f);
}

// ---------------------------------------------------------------------------
// Phase 2: recurrence. grid=64 blocks, block=64 threads (1 wave).
// Lane l owns outputs j=l and j=l+64; W_hh rows in registers (256 VGPRs).
// ---------------------------------------------------------------------------
__global__ __launch_bounds__(64, 1) void rnn_scan(
    const float* __restrict__ xp, const float* __restrict__ Whh,
    const float* __restrict__ bhh, const float* __restrict__ bh,
    const float* __restrict__ Wfc, const float* __restrict__ bfc,
    float* __restrict__ out) {
  const int b = blockIdx.x;
  const int l = threadIdx.x;  // 0..63

  __shared__ float4 hs4[RNN_H / 4];
  float* hs = (float*)hs4;

  // load W_hh rows l and l+64 into registers
  float w0[RNN_H], w1[RNN_H];
#pragma unroll
  for (int k4 = 0; k4 < RNN_H / 4; ++k4) {
    const float4 v0 = *(const float4*)&Whh[(size_t)l * RNN_H + k4 * 4];
    w0[k4 * 4 + 0] = v0.x; w0[k4 * 4 + 1] = v0.y;
    w0[k4 * 4 + 2] = v0.z; w0[k4 * 4 + 3] = v0.w;
    const float4 v1 = *(const float4*)&Whh[(size_t)(l + 64) * RNN_H + k4 * 4];
    w1[k4 * 4 + 0] = v1.x; w1[k4 * 4 + 1] = v1.y;
    w1[k4 * 4 + 2] = v1.z; w1[k4 * 4 + 3] = v1.w;
  }

  const float bias0 = bhh[l] + bh[l];
  const float bias1 = bhh[l + 64] + bh[l + 64];

  hs[l] = 0.f;
  hs[l + 64] = 0.f;
  __syncthreads();

  const float* xpb = xp + (size_t)b * RNN_S * RNN_H;

  // software-pipelined xp loads, depth 2
  float pA0 = xpb[l],            pA1 = xpb[l + 64];
  float pB0 = xpb[RNN_H + l],    pB1 = xpb[RNN_H + l + 64];

#pragma unroll 1
  for (int t = 0; t < RNN_S; ++t) {
    // split accumulators to shorten FMA dependency chains
    float a0a = bias0 + pA0, a0b = 0.f;
    float a1a = bias1 + pA1, a1b = 0.f;

    pA0 = pB0; pA1 = pB1;
    const int tt = (t + 2 < RNN_S) ? (t + 2) : (RNN_S - 1);
    pB0 = xpb[(size_t)tt * RNN_H + l];
    pB1 = xpb[(size_t)tt * RNN_H + l + 64];

#pragma unroll
    for (int g = 0; g < 8; ++g) {
      const float4 h0 = hs4[g * 4 + 0];
      const float4 h1 = hs4[g * 4 + 1];
      const float4 h2 = hs4[g * 4 + 2];
      const float4 h3 = hs4[g * 4 + 3];
      const int k = g * 16;
      a0a += w0[k + 0] * h0.x + w0[k + 1] * h0.y + w0[k + 2] * h0.z + w0[k + 3] * h0.w;
      a1a += w1[k + 0] * h0.x + w1[k + 1] * h0.y + w1[k + 2] * h0.z + w1[k + 3] * h0.w;
      a0b += w0[k + 4] * h1.x + w0[k + 5] * h1.y + w0[k + 6] * h1.z + w0[k + 7] * h1.w;
      a1b += w1[k + 4] * h1.x + w1[k + 5] * h1.y + w1[k + 6] * h1.z + w1[k + 7] * h1.w;
      a0a += w0[k + 8] * h2.x + w0[k + 9] * h2.y + w0[k + 10] * h2.z + w0[k + 11] * h2.w;
      a1a += w1[k + 8] * h2.x + w1[k + 9] * h2.y + w1[k + 10] * h2.z + w1[k + 11] * h2.w;
      a0b += w0[k + 12] * h3.x + w0[k + 13] * h3.y + w0[k + 14] * h3.z + w0[k + 15] * h3.w;
      a1b += w1[k + 12] * h3.x + w1[k + 13] * h3.y + w1[k + 14] * h3.z + w1[k + 15] * h3.w;
    }

    const float t0 = fast_tanh(a0a + a0b);
    const float t1 = fast_tanh(a1a + a1b);
    __syncthreads();           // all reads of old h done
    hs[l] = t0;
    hs[l + 64] = t1;
    __syncthreads();           // new h visible
  }

  // fused FC: out[b][o] = sum_k hs[k] * Wfc[o][k] + bfc[o]
  if (l < RNN_OUT) {
    float s = bfc[l];
#pragma unroll
    for (int k4 = 0; k4 < RNN_H / 4; ++k4) {
      const float4 w = *(const float4*)&Wfc[(size_t)l * RNN_H + k4 * 4];
      const float4 h = hs4[k4];
      s += w.x * h.x + w.y * h.y + w.z * h.z + w.w * h.w;
    }
    out[b * RNN_OUT + l] = s;
  }
}

extern "C" void kernel_launch(void* const* d_in, const int* in_sizes, int n_in,
                              void* d_out, int out_size, void* d_ws, size_t ws_size,
                              hipStream_t stream) {
  const float* x   = (const float*)d_in[0];
  const float* Wxh = (const float*)d_in[1];
  const float* bxh = (const float*)d_in[2];
  const float* Whh = (const float*)d_in[3];
  const float* bhh = (const float*)d_in[4];
  const float* bh  = (const float*)d_in[5];
  const float* Wfc = (const float*)d_in[6];
  const float* bfc = (const float*)d_in[7];
  float* out = (float*)d_out;
  float* xp  = (float*)d_ws;  // needs 131072*128*4 = 64 MiB of workspace

  xproj_gemm<<<dim3((RNN_B * RNN_S) / 128), dim3(256), 0, stream>>>(x, Wxh, bxh, xp);
  rnn_scan<<<dim3(RNN_B), dim3(64), 0, stream>>>(xp, Whh, bhh, bh, Wfc, bfc, out);
}

// Round 2
// 2194.352 us; speedup vs baseline: 1.2435x; 1.2435x over previous
//
#include <hip/hip_runtime.h>
#include <hip/hip_bf16.h>

// SimpleRNN: B=64, S=2048, IN=256, H=128, OUT=3 (all fp32)
// Phase 1: xproj[b,s,:] = x[b,s,:] @ W_xh^T + b_xh   -> d_ws (64 MiB)
// Phase 2: 2048-step recurrence, 1 workgroup (2 waves, 128 threads) per batch
//          element. Lane owns ONE output row -> w[128] fits in arch VGPRs
//          (round-1 version needed 256 -> AGPR/scratch demotion, 2820 cyc/step).
//          h in LDS, broadcast ds_read_b128, fused final FC.

#define RNN_B   64
#define RNN_S   2048
#define RNN_IN  256
#define RNN_H   128
#define RNN_OUT 3

// ---------------------------------------------------------------------------
// Phase 1: fp32 tiled GEMM  C[M=131072, N=128] = A[M,256] * B[128,256]^T
// Tile: BM=128, BN=128, BK=32; 256 threads, 8x8 per-thread tile.
// LDS rows padded to 132 floats (528 B): 16B-aligned so inner loop uses
// ds_read_b128 (round-1's +1 pad forced scalar ds_read_b32 -> LDS-bound).
// ---------------------------------------------------------------------------
__global__ __launch_bounds__(256) void xproj_gemm(
    const float* __restrict__ x, const float* __restrict__ Wxh,
    const float* __restrict__ bxh, float* __restrict__ xp) {
  __shared__ __align__(16) float As[32][132];  // [k][m]
  __shared__ __align__(16) float Bs[32][132];  // [k][n]

  const int tid = threadIdx.x;
  const int m0 = blockIdx.x * 128;
  const int tn = (tid & 15) * 8;   // n offset 0..120
  const int tm = (tid >> 4) * 8;   // m offset 0..120

  float acc[8][8];
#pragma unroll
  for (int i = 0; i < 8; ++i)
#pragma unroll
    for (int j = 0; j < 8; ++j) acc[i][j] = 0.f;

  const int c = (tid & 7) * 4;   // k sub-col (float4)
  const int r0 = tid >> 3;       // row 0..31

  for (int kc = 0; kc < RNN_IN; kc += 32) {
#pragma unroll
    for (int p = 0; p < 4; ++p) {
      const int row = r0 + 32 * p;
      const float4 va = *(const float4*)&x[(size_t)(m0 + row) * RNN_IN + kc + c];
      As[c + 0][row] = va.x; As[c + 1][row] = va.y;
      As[c + 2][row] = va.z; As[c + 3][row] = va.w;
      const float4 vb = *(const float4*)&Wxh[(size_t)row * RNN_IN + kc + c];
      Bs[c + 0][row] = vb.x; Bs[c + 1][row] = vb.y;
      Bs[c + 2][row] = vb.z; Bs[c + 3][row] = vb.w;
    }
    __syncthreads();
#pragma unroll
    for (int k = 0; k < 32; ++k) {
      const float4 a0 = *(const float4*)&As[k][tm];
      const float4 a1 = *(const float4*)&As[k][tm + 4];
      const float4 b0 = *(const float4*)&Bs[k][tn];
      const float4 b1 = *(const float4*)&Bs[k][tn + 4];
      const float a[8] = {a0.x, a0.y, a0.z, a0.w, a1.x, a1.y, a1.z, a1.w};
      const float b[8] = {b0.x, b0.y, b0.z, b0.w, b1.x, b1.y, b1.z, b1.w};
#pragma unroll
      for (int i = 0; i < 8; ++i)
#pragma unroll
        for (int j = 0; j < 8; ++j) acc[i][j] += a[i] * b[j];
    }
    __syncthreads();
  }

#pragma unroll
  for (int i = 0; i < 8; ++i) {
    const size_t row = (size_t)(m0 + tm + i);
#pragma unroll
    for (int j = 0; j < 8; j += 4) {
      float4 v;
      v.x = acc[i][j + 0] + bxh[tn + j + 0];
      v.y = acc[i][j + 1] + bxh[tn + j + 1];
      v.z = acc[i][j + 2] + bxh[tn + j + 2];
      v.w = acc[i][j + 3] + bxh[tn + j + 3];
      *(float4*)&xp[row * RNN_H + tn + j] = v;
    }
  }
}

// fast tanh: 1 - 2/(exp(2x)+1); saturates correctly at +-inf
__device__ __forceinline__ float fast_tanh(float a) {
  const float e = __expf(2.f * a);
  return 1.f - 2.f / (e + 1.f);
}

// ---------------------------------------------------------------------------
// Phase 2: recurrence. grid=64 blocks, block=128 threads (2 waves).
// Thread j owns output row j; W_hh row j in 128 VGPRs (no AGPR demotion).
// h[128] in LDS; reads are wave-broadcast (same address all lanes).
// ---------------------------------------------------------------------------
__global__ __launch_bounds__(128, 1) void rnn_scan(
    const float* __restrict__ xp, const float* __restrict__ Whh,
    const float* __restrict__ bhh, const float* __restrict__ bh,
    const float* __restrict__ Wfc, const float* __restrict__ bfc,
    float* __restrict__ out) {
  const int b = blockIdx.x;
  const int j = threadIdx.x;  // 0..127 = output row

  __shared__ __align__(16) float4 hs4[RNN_H / 4];
  float* hs = (float*)hs4;

  // W_hh row j -> registers (128 VGPRs)
  float w[RNN_H];
#pragma unroll
  for (int k4 = 0; k4 < RNN_H / 4; ++k4) {
    const float4 v = *(const float4*)&Whh[(size_t)j * RNN_H + k4 * 4];
    w[k4 * 4 + 0] = v.x; w[k4 * 4 + 1] = v.y;
    w[k4 * 4 + 2] = v.z; w[k4 * 4 + 3] = v.w;
  }

  const float bias = bhh[j] + bh[j];

  hs[j] = 0.f;
  __syncthreads();

  const float* xpb = xp + (size_t)b * RNN_S * RNN_H;

  // software-pipelined xp loads, depth 4 (covers ~HBM latency at ~450 cyc/step)
  float p0 = xpb[0 * RNN_H + j];
  float p1 = xpb[1 * RNN_H + j];
  float p2 = xpb[2 * RNN_H + j];
  float p3 = xpb[3 * RNN_H + j];

#pragma unroll 1
  for (int t = 0; t < RNN_S; ++t) {
    float acc0 = bias + p0, acc1 = 0.f, acc2 = 0.f, acc3 = 0.f;

    p0 = p1; p1 = p2; p2 = p3;
    const int tt = (t + 4 < RNN_S) ? (t + 4) : (RNN_S - 1);
    p3 = xpb[(size_t)tt * RNN_H + j];

#pragma unroll
    for (int g = 0; g < 8; ++g) {
      const float4 h0 = hs4[g * 4 + 0];
      const float4 h1 = hs4[g * 4 + 1];
      const float4 h2 = hs4[g * 4 + 2];
      const float4 h3 = hs4[g * 4 + 3];
      const int k = g * 16;
      acc0 += w[k + 0] * h0.x + w[k + 1] * h0.y + w[k + 2] * h0.z + w[k + 3] * h0.w;
      acc1 += w[k + 4] * h1.x + w[k + 5] * h1.y + w[k + 6] * h1.z + w[k + 7] * h1.w;
      acc2 += w[k + 8] * h2.x + w[k + 9] * h2.y + w[k + 10] * h2.z + w[k + 11] * h2.w;
      acc3 += w[k + 12] * h3.x + w[k + 13] * h3.y + w[k + 14] * h3.z + w[k + 15] * h3.w;
    }

    const float hv = fast_tanh((acc0 + acc1) + (acc2 + acc3));
    __syncthreads();           // all broadcast reads of old h done
    hs[j] = hv;
    __syncthreads();           // new h visible to both waves
  }

  // fused FC: out[b][o] = sum_k hs[k] * Wfc[o][k] + bfc[o]
  if (j < RNN_OUT) {
    float s = bfc[j];
#pragma unroll
    for (int k4 = 0; k4 < RNN_H / 4; ++k4) {
      const float4 wf = *(const float4*)&Wfc[(size_t)j * RNN_H + k4 * 4];
      const float4 h = hs4[k4];
      s += wf.x * h.x + wf.y * h.y + wf.z * h.z + wf.w * h.w;
    }
    out[b * RNN_OUT + j] = s;
  }
}

extern "C" void kernel_launch(void* const* d_in, const int* in_sizes, int n_in,
                              void* d_out, int out_size, void* d_ws, size_t ws_size,
                              hipStream_t stream) {
  const float* x   = (const float*)d_in[0];
  const float* Wxh = (const float*)d_in[1];
  const float* bxh = (const float*)d_in[2];
  const float* Whh = (const float*)d_in[3];
  const float* bhh = (const float*)d_in[4];
  const float* bh  = (const float*)d_in[5];
  const float* Wfc = (const float*)d_in[6];
  const float* bfc = (const float*)d_in[7];
  float* out = (float*)d_out;
  float* xp  = (float*)d_ws;  // 131072*128*4 = 64 MiB

  xproj_gemm<<<dim3((RNN_B * RNN_S) / 128), dim3(256), 0, stream>>>(x, Wxh, bxh, xp);
  rnn_scan<<<dim3(RNN_B), dim3(128), 0, stream>>>(xp, Whh, bhh, bh, Wfc, bfc, out);
}

// Round 3
// 1333.710 us; speedup vs baseline: 2.0459x; 1.6453x over previous
//
#include <hip/hip_runtime.h>
#include <hip/hip_bf16.h>

// SimpleRNN: B=64, S=2048, IN=256, H=128, OUT=3 (all fp32)
// Phase 1: xproj[b,s,:] = x[b,s,:] @ W_xh^T + b_xh   -> d_ws (64 MiB)  [unchanged]
// Phase 2: 2048-step recurrence, 64 blocks x 128 threads (2 waves).
//   Round-2 failure modes fixed here:
//   (a) VGPR_Count=92 proved w[128] was NOT register-resident -> 32 NAMED
//       float4 registers via macros.
//   (b) __syncthreads() drains vmcnt(0) every step, killing the xp prefetch
//       pipeline -> CK-style block_sync_lds() (lgkmcnt-only) keeps global
//       loads in flight across the barrier.
//   (c) double-buffered h -> ONE barrier per step; manual 4x unroll gives
//       static buffer parity + 4-deep prefetch with no register shifting.

#define RNN_B   64
#define RNN_S   2048
#define RNN_IN  256
#define RNN_H   128
#define RNN_OUT 3

// ---------------------------------------------------------------------------
// Phase 1: fp32 tiled GEMM  C[M=131072, N=128] = A[M,256] * B[128,256]^T
// (byte-identical to round 2 for attribution)
// ---------------------------------------------------------------------------
__global__ __launch_bounds__(256) void xproj_gemm(
    const float* __restrict__ x, const float* __restrict__ Wxh,
    const float* __restrict__ bxh, float* __restrict__ xp) {
  __shared__ __align__(16) float As[32][132];  // [k][m]
  __shared__ __align__(16) float Bs[32][132];  // [k][n]

  const int tid = threadIdx.x;
  const int m0 = blockIdx.x * 128;
  const int tn = (tid & 15) * 8;   // n offset 0..120
  const int tm = (tid >> 4) * 8;   // m offset 0..120

  float acc[8][8];
#pragma unroll
  for (int i = 0; i < 8; ++i)
#pragma unroll
    for (int j = 0; j < 8; ++j) acc[i][j] = 0.f;

  const int c = (tid & 7) * 4;   // k sub-col (float4)
  const int r0 = tid >> 3;       // row 0..31

  for (int kc = 0; kc < RNN_IN; kc += 32) {
#pragma unroll
    for (int p = 0; p < 4; ++p) {
      const int row = r0 + 32 * p;
      const float4 va = *(const float4*)&x[(size_t)(m0 + row) * RNN_IN + kc + c];
      As[c + 0][row] = va.x; As[c + 1][row] = va.y;
      As[c + 2][row] = va.z; As[c + 3][row] = va.w;
      const float4 vb = *(const float4*)&Wxh[(size_t)row * RNN_IN + kc + c];
      Bs[c + 0][row] = vb.x; Bs[c + 1][row] = vb.y;
      Bs[c + 2][row] = vb.z; Bs[c + 3][row] = vb.w;
    }
    __syncthreads();
#pragma unroll
    for (int k = 0; k < 32; ++k) {
      const float4 a0 = *(const float4*)&As[k][tm];
      const float4 a1 = *(const float4*)&As[k][tm + 4];
      const float4 b0 = *(const float4*)&Bs[k][tn];
      const float4 b1 = *(const float4*)&Bs[k][tn + 4];
      const float a[8] = {a0.x, a0.y, a0.z, a0.w, a1.x, a1.y, a1.z, a1.w};
      const float b[8] = {b0.x, b0.y, b0.z, b0.w, b1.x, b1.y, b1.z, b1.w};
#pragma unroll
      for (int i = 0; i < 8; ++i)
#pragma unroll
        for (int j = 0; j < 8; ++j) acc[i][j] += a[i] * b[j];
    }
    __syncthreads();
  }

#pragma unroll
  for (int i = 0; i < 8; ++i) {
    const size_t row = (size_t)(m0 + tm + i);
#pragma unroll
    for (int j = 0; j < 8; j += 4) {
      float4 v;
      v.x = acc[i][j + 0] + bxh[tn + j + 0];
      v.y = acc[i][j + 1] + bxh[tn + j + 1];
      v.z = acc[i][j + 2] + bxh[tn + j + 2];
      v.w = acc[i][j + 3] + bxh[tn + j + 3];
      *(float4*)&xp[row * RNN_H + tn + j] = v;
    }
  }
}

// fast tanh: 1 - 2/(exp(2x)+1); saturates correctly at +-inf
__device__ __forceinline__ float fast_tanh(float a) {
  const float e = __expf(2.f * a);
  return 1.f - 2.f / (e + 1.f);
}

// CK-style LDS-only barrier: does NOT drain vmcnt, so global prefetch loads
// stay in flight across the barrier (HIP __syncthreads emits vmcnt(0) too).
__device__ __forceinline__ void block_sync_lds() {
  asm volatile("s_waitcnt lgkmcnt(0)" ::: "memory");
  __builtin_amdgcn_s_barrier();
}

// 32 named float4 weight registers (w0..w31): named SSA values force the
// register allocator's hand (round-2's float w[128] array stayed in memory,
// VGPR_Count=92).
#define RNN_W_LIST(M) \
  M(0)  M(1)  M(2)  M(3)  M(4)  M(5)  M(6)  M(7)  \
  M(8)  M(9)  M(10) M(11) M(12) M(13) M(14) M(15) \
  M(16) M(17) M(18) M(19) M(20) M(21) M(22) M(23) \
  M(24) M(25) M(26) M(27) M(28) M(29) M(30) M(31)

#define WDECL(i) float4 w##i;
#define WLOAD(i) w##i = wrow[i];

#define WFMA(i, a) {                              \
    const float4 h4 = hb_in[i];                   \
    a = fmaf(w##i.x, h4.x, a);                    \
    a = fmaf(w##i.y, h4.y, a);                    \
    a = fmaf(w##i.z, h4.z, a);                    \
    a = fmaf(w##i.w, h4.w, a);                    \
  }

#define RNN_MATVEC \
  WFMA(0,  acc0) WFMA(1,  acc1) WFMA(2,  acc2) WFMA(3,  acc3) \
  WFMA(4,  acc0) WFMA(5,  acc1) WFMA(6,  acc2) WFMA(7,  acc3) \
  WFMA(8,  acc0) WFMA(9,  acc1) WFMA(10, acc2) WFMA(11, acc3) \
  WFMA(12, acc0) WFMA(13, acc1) WFMA(14, acc2) WFMA(15, acc3) \
  WFMA(16, acc0) WFMA(17, acc1) WFMA(18, acc2) WFMA(19, acc3) \
  WFMA(20, acc0) WFMA(21, acc1) WFMA(22, acc2) WFMA(23, acc3) \
  WFMA(24, acc0) WFMA(25, acc1) WFMA(26, acc2) WFMA(27, acc3) \
  WFMA(28, acc0) WFMA(29, acc1) WFMA(30, acc2) WFMA(31, acc3)

// One step: read h from BIN (broadcast ds_read_b128), matvec from named regs,
// tanh, write h[j] to BOUT, single LDS-only barrier. PREG is consumed then
// refilled with xp[TNEXT] (stays in flight ~4 steps; barrier never drains it).
#define RNN_STEP(BIN, BOUT, PREG, TNEXT)                              \
  {                                                                   \
    const float4* hb_in = (const float4*)(BIN);                       \
    float acc0 = bias + PREG, acc1 = 0.f, acc2 = 0.f, acc3 = 0.f;     \
    PREG = xpb[(size_t)(TNEXT) * RNN_H + j];                          \
    RNN_MATVEC                                                        \
    (BOUT)[j] = fast_tanh((acc0 + acc1) + (acc2 + acc3));             \
    block_sync_lds();                                                 \
  }

// ---------------------------------------------------------------------------
// Phase 2: recurrence. grid=64 blocks, block=128 threads (2 waves).
// Thread j owns output row j; W_hh row j in 32 named float4 VGPRs.
// h double-buffered in LDS; 1 barrier/step; 4-deep global prefetch.
// ---------------------------------------------------------------------------
__global__ __launch_bounds__(128, 1) void rnn_scan(
    const float* __restrict__ xp, const float* __restrict__ Whh,
    const float* __restrict__ bhh, const float* __restrict__ bh,
    const float* __restrict__ Wfc, const float* __restrict__ bfc,
    float* __restrict__ out) {
  const int b = blockIdx.x;
  const int j = threadIdx.x;  // 0..127 = output row

  __shared__ __align__(16) float hsA[RNN_H];
  __shared__ __align__(16) float hsB[RNN_H];

  const float4* wrow = (const float4*)&Whh[(size_t)j * RNN_H];
  RNN_W_LIST(WDECL)
  RNN_W_LIST(WLOAD)

  const float bias = bhh[j] + bh[j];

  hsA[j] = 0.f;
  block_sync_lds();

  const float* xpb = xp + (size_t)b * RNN_S * RNN_H;

  // 4-deep prefetch, one register per unrolled body (no shifting movs --
  // shifting would force a vmcnt wait one step after issue).
  float p0 = xpb[0 * RNN_H + j];
  float p1 = xpb[1 * RNN_H + j];
  float p2 = xpb[2 * RNN_H + j];
  float p3 = xpb[3 * RNN_H + j];

#pragma unroll 1
  for (int t = 0; t < RNN_S; t += 4) {
    const int n0 = (t + 4 < RNN_S) ? t + 4 : RNN_S - 1;
    const int n1 = (t + 5 < RNN_S) ? t + 5 : RNN_S - 1;
    const int n2 = (t + 6 < RNN_S) ? t + 6 : RNN_S - 1;
    const int n3 = (t + 7 < RNN_S) ? t + 7 : RNN_S - 1;
    RNN_STEP(hsA, hsB, p0, n0)
    RNN_STEP(hsB, hsA, p1, n1)
    RNN_STEP(hsA, hsB, p2, n2)
    RNN_STEP(hsB, hsA, p3, n3)
  }
  // after 2048 steps the final h is in hsA (last body writes hsA), and the
  // trailing block_sync_lds makes it visible.

  // fused FC: out[b][o] = sum_k hs[k] * Wfc[o][k] + bfc[o]
  if (j < RNN_OUT) {
    float s = bfc[j];
    const float4* hf = (const float4*)hsA;
#pragma unroll
    for (int k4 = 0; k4 < RNN_H / 4; ++k4) {
      const float4 wf = *(const float4*)&Wfc[(size_t)j * RNN_H + k4 * 4];
      const float4 h = hf[k4];
      s = fmaf(wf.x, h.x, s); s = fmaf(wf.y, h.y, s);
      s = fmaf(wf.z, h.z, s); s = fmaf(wf.w, h.w, s);
    }
    out[b * RNN_OUT + j] = s;
  }
}

extern "C" void kernel_launch(void* const* d_in, const int* in_sizes, int n_in,
                              void* d_out, int out_size, void* d_ws, size_t ws_size,
                              hipStream_t stream) {
  const float* x   = (const float*)d_in[0];
  const float* Wxh = (const float*)d_in[1];
  const float* bxh = (const float*)d_in[2];
  const float* Whh = (const float*)d_in[3];
  const float* bhh = (const float*)d_in[4];
  const float* bh  = (const float*)d_in[5];
  const float* Wfc = (const float*)d_in[6];
  const float* bfc = (const float*)d_in[7];
  float* out = (float*)d_out;
  float* xp  = (float*)d_ws;  // 131072*128*4 = 64 MiB

  xproj_gemm<<<dim3((RNN_B * RNN_S) / 128), dim3(256), 0, stream>>>(x, Wxh, bxh, xp);
  rnn_scan<<<dim3(RNN_B), dim3(128), 0, stream>>>(xp, Whh, bhh, bh, Wfc, bfc, out);
}